// Round 4
// baseline (13726.054 us; speedup 1.0000x reference)
//
#include <hip/hip_runtime.h>
#include <hip/hip_bf16.h>
#include <hip/hip_fp16.h>
#include <math.h>

// Problem constants (from reference)
#define BB 256
#define TT 256
// H = [128,32,32], TH=192, ZDIM=64, ATT=4

__device__ __forceinline__ float sigf(float x) { return 1.f / (1.f + expf(-x)); }

// lgkm-only barrier: drains LDS ops but lets global loads stay in flight
// across the barrier (the compiler's __syncthreads would emit vmcnt(0)).
// 0xC07F = vmcnt 63 (no wait), expcnt 7 (no wait), lgkmcnt 0 (wait all LDS).
#define BAR() do {                                   \
    __atomic_signal_fence(__ATOMIC_SEQ_CST);         \
    __builtin_amdgcn_s_waitcnt(0xC07F);              \
    __builtin_amdgcn_s_barrier();                    \
    __atomic_signal_fence(__ATOMIC_SEQ_CST);         \
} while (0)

// ---------------------------------------------------------------------------
// fp32 -> fp16 conversion
// ---------------------------------------------------------------------------
__global__ void f2h(const float* __restrict__ s, __half* __restrict__ d, int n) {
    int i = blockIdx.x * 256 + threadIdx.x;
    if (i < n) d[i] = __float2half(s[i]);
}

// ---------------------------------------------------------------------------
// Kernel 1: G = X @ W + bias   (X: [M,K], W: [K,N], G: [M,N]), OT = fp32|fp16
// ---------------------------------------------------------------------------
#define GT_M 128
#define GT_N 64
#define GT_K 16

__device__ __forceinline__ void stvec4(float* p, float4 v) { *(float4*)p = v; }
__device__ __forceinline__ void stvec4(__half* p, float4 v) {
    __half2 h01 = __floats2half2_rn(v.x, v.y);
    __half2 h23 = __floats2half2_rn(v.z, v.w);
    *(__half2*)p = h01;
    *(__half2*)(p + 2) = h23;
}

template <typename OT>
__global__ __launch_bounds__(256)
void xw_gemm(const float* __restrict__ X, const float* __restrict__ W,
             const float* __restrict__ bias, OT* __restrict__ G,
             int M, int N, int K) {
    __shared__ float As[GT_K][GT_M + 4];
    __shared__ float Bs[GT_K][GT_N];
    const int tid = threadIdx.x;
    const int bm = blockIdx.y * GT_M;
    const int bn = blockIdx.x * GT_N;
    const int tx = tid & 15;
    const int ty = tid >> 4;

    float acc[8][4];
#pragma unroll
    for (int i = 0; i < 8; ++i)
#pragma unroll
        for (int j = 0; j < 4; ++j) acc[i][j] = 0.f;

    for (int kt = 0; kt < K; kt += GT_K) {
#pragma unroll
        for (int i = 0; i < 8; ++i) {
            int idx = i * 256 + tid;
            int m = idx >> 4, k = idx & 15;
            int gk = kt + k;
            As[k][m] = (gk < K) ? X[(size_t)(bm + m) * K + gk] : 0.f;
        }
#pragma unroll
        for (int i = 0; i < 4; ++i) {
            int idx = i * 256 + tid;
            int k = idx >> 6, n = idx & 63;
            int gk = kt + k;
            Bs[k][n] = (gk < K) ? W[(size_t)gk * N + bn + n] : 0.f;
        }
        __syncthreads();
#pragma unroll
        for (int k = 0; k < GT_K; ++k) {
            float a[8], b[4];
            const float4 a0 = *(const float4*)&As[k][ty * 8];
            const float4 a1 = *(const float4*)&As[k][ty * 8 + 4];
            const float4 bv = *(const float4*)&Bs[k][tx * 4];
            a[0]=a0.x; a[1]=a0.y; a[2]=a0.z; a[3]=a0.w;
            a[4]=a1.x; a[5]=a1.y; a[6]=a1.z; a[7]=a1.w;
            b[0]=bv.x; b[1]=bv.y; b[2]=bv.z; b[3]=bv.w;
#pragma unroll
            for (int i = 0; i < 8; ++i)
#pragma unroll
                for (int j = 0; j < 4; ++j) acc[i][j] += a[i] * b[j];
        }
        __syncthreads();
    }
    const int n0 = bn + tx * 4;
#pragma unroll
    for (int i = 0; i < 8; ++i) {
        int m = bm + ty * 8 + i;
        float4 v;
        v.x = acc[i][0] + bias[n0 + 0];
        v.y = acc[i][1] + bias[n0 + 1];
        v.z = acc[i][2] + bias[n0 + 2];
        v.w = acc[i][3] + bias[n0 + 3];
        stvec4(&G[(size_t)m * N + n0], v);
    }
}

// ---------------------------------------------------------------------------
// Kernel 2: persistent recurrence. 128 blocks x 512 threads, 2 rows/block.
// fp16 weights; lgkm-only barriers; 8-deep cross-barrier register prefetch
// per stage; G-values prefetched one step ahead; comp2 weights LDS-resident.
// ---------------------------------------------------------------------------
__global__ __launch_bounds__(512, 2)
void marn_rec(const float* __restrict__ G0, const __half* __restrict__ G1h,
              const __half* __restrict__ G2h,
              const __half* __restrict__ hU0, const __half* __restrict__ hV0,
              const __half* __restrict__ hU1, const __half* __restrict__ hV1,
              const __half* __restrict__ hU2, const __half* __restrict__ hV2,
              const __half* __restrict__ haw1, const float* __restrict__ ab1,
              const __half* __restrict__ haw2, const float* __restrict__ ab2,
              const __half* __restrict__ hcw10, const float* __restrict__ cb10,
              const float* __restrict__ cw20, const float* __restrict__ cb20,
              const __half* __restrict__ hcw11, const float* __restrict__ cb11,
              const float* __restrict__ cw21, const float* __restrict__ cb21,
              const __half* __restrict__ hcw12, const float* __restrict__ cb12,
              const float* __restrict__ cw22, const float* __restrict__ cb22,
              const float* __restrict__ fw1, const float* __restrict__ fb1,
              const float* __restrict__ fw2, const float* __restrict__ fb2,
              float* __restrict__ out) {
    // state: hz = [h0(128)|h1(32)|h2(32)|z(64)]
    __shared__ float hz[2][256];
    __shared__ float cst[2][192];
    __shared__ float a1s[2][256];
    __shared__ float attE[2][768];
    __shared__ float aout[2][768];
    __shared__ float hid[2][128];
    __shared__ float red[2][4];
    __shared__ float scratch[7680];   // 30KB, aliased across stages
    __shared__ float c2w[3072];       // cw20(2048) | cw21(512) | cw22(512)

    const int tid = threadIdx.x;
    const int row0 = blockIdx.x * 2;

    for (int i = tid; i < 2 * 256; i += 512) (&hz[0][0])[i] = 0.f;
    for (int i = tid; i < 2 * 192; i += 512) (&cst[0][0])[i] = 0.f;
    for (int i = tid; i < 2048; i += 512) c2w[i] = cw20[i];
    if (tid < 512) { c2w[2048 + tid] = cw21[tid]; c2w[2560 + tid] = cw22[tid]; }
    __syncthreads();

    // ---- per-thread precompute for stage A (480 active threads) ----
    const __half* WBa = nullptr; int HOa = 0, STRa = 0, SOa = 0, SRa = 0;
    if (tid < 384) {
        const int g = tid & 63, kc = tid >> 6;         // kc 0..5
        const int cb = g * 8;
        if (kc < 4) { WBa = hU0 + (size_t)(32 * kc) * 512 + cb; HOa = 32 * kc; }
        else        { WBa = hV0 + (size_t)(32 * (kc - 4)) * 512 + cb; HOa = 192 + 32 * (kc - 4); }
        STRa = 512;
        SOa = kc * 1024 + cb;      // + r*512
        SRa = 512;
    } else if (tid < 480) {
        const int u = tid - 384;                       // 0..95
        const int kc = u >> 5;                         // 0..2
        const int g2 = u & 31;
        const int cell = g2 >> 4;                      // 0|1
        const int cb = (g2 & 15) * 8;
        const __half* Uc = cell ? hU2 : hU1;
        const __half* Vc = cell ? hV2 : hV1;
        if (kc == 0) { WBa = Uc + cb; HOa = 128 + 32 * cell; }
        else         { WBa = Vc + (size_t)(32 * (kc - 1)) * 128 + cb; HOa = 192 + 32 * (kc - 1); }
        STRa = 128;
        SOa = 6144 + kc * 512 + cell * 128 + cb;   // + r*256
        SRa = 256;
    }
    // att1 precompute (256 active)
    const __half* WB1 = nullptr; int HO1 = 0, SO1 = 0;
    if (tid < 256) {
        const int g = tid & 31, kc = tid >> 5;         // kc 0..7
        const int cb = g * 8;
        WB1 = haw1 + (size_t)(24 * kc) * 256 + cb;
        HO1 = 24 * kc;
        SO1 = kc * 512 + cb;       // + r*256
    }
    // att2 precompute (384 active)
    const int kc2 = tid / 96;
    const int g2a = tid - kc2 * 96;
    const __half* WB2 = haw2 + (size_t)(64 * kc2) * 768 + g2a * 8;
    const int HO2 = 64 * kc2;
    const int SO2 = kc2 * 1536 + g2a * 8;              // + r*768
    // comp1 precompute (320 active)
    const __half* WBc = nullptr; int HOc = 0, SOc = 0, KNc = 0;
    if (tid < 256) {
        const int g = tid & 7, kc = tid >> 3;          // kc 0..31
        WBc = hcw10 + (size_t)(16 * kc) * 64 + g * 8;
        HOc = 16 * kc;
        SOc = kc * 128 + g * 8;    // + r*64
        KNc = 64;
    } else if (tid < 320) {
        const int u = tid - 256;                       // 0..63
        const int cell = u >> 5;
        const int rem = u & 31;
        const int g = rem & 3, kc = rem >> 2;          // kc 0..7
        WBc = (cell ? hcw12 : hcw11) + (size_t)(16 * kc) * 32 + g * 8;
        HOc = 512 + 128 * cell + 16 * kc;
        SOc = 4096 + cell * 512 + kc * 64 + g * 8;     // + r*32
        KNc = 32;
    }
    // gates G-prefetch address precompute
    const int gr_r  = (tid < 256) ? (tid >> 7) : (((tid - 256) >> 6) & 1);
    const int gr_u  = tid & 127;                         // cell0 col (tid<256)
    const int g12_u6   = (tid - 256) & 63;
    const int g12_cell = g12_u6 >> 5;
    const int g12_uu   = g12_u6 & 31;

    // prefetch buffers (cross-barrier, in-flight global loads)
    float4 pfA[8], pf1[8], pf2[8], pfc[8];
    float  g0p[4];
    __half g12p[4];

    // ---- pre-loop prefetch for t = 0 ----
    if (tid < 480) {
#pragma unroll
        for (int k = 0; k < 8; ++k) pfA[k] = *(const float4*)(WBa + (size_t)k * STRa);
    }
    if (tid < 256) {
        const float* gp = G0 + ((size_t)(row0 + gr_r) * TT + 0) * 512;
#pragma unroll
        for (int q = 0; q < 4; ++q) g0p[q] = gp[q * 128 + gr_u];
    } else if (tid < 384) {
        const __half* gp = (g12_cell ? G2h : G1h) + ((size_t)(row0 + gr_r) * TT + 0) * 128;
#pragma unroll
        for (int q = 0; q < 4; ++q) g12p[q] = gp[q * 32 + g12_uu];
    }

    for (int t = 0; t < TT; ++t) {
        // ============ stage A compute: partials of [h|z]@[U;V] ============
        if (tid < 480) {
            float acc0[8], acc1[8];
#pragma unroll
            for (int j = 0; j < 8; ++j) { acc0[j] = 0.f; acc1[j] = 0.f; }
            // prefetched first 8 k
#pragma unroll
            for (int k = 0; k < 8; ++k) {
                const __half* hw = (const __half*)&pfA[k];
                const float a0 = hz[0][HOa + k];
                const float a1 = hz[1][HOa + k];
#pragma unroll
                for (int j = 0; j < 8; ++j) {
                    const float w = __half2float(hw[j]);
                    acc0[j] += w * a0;
                    acc1[j] += w * a1;
                }
            }
#pragma unroll 8
            for (int k = 8; k < 32; ++k) {
                const float4 wv = *(const float4*)(WBa + (size_t)k * STRa);
                const __half* hw = (const __half*)&wv;
                const float a0 = hz[0][HOa + k];
                const float a1 = hz[1][HOa + k];
#pragma unroll
                for (int j = 0; j < 8; ++j) {
                    const float w = __half2float(hw[j]);
                    acc0[j] += w * a0;
                    acc1[j] += w * a1;
                }
            }
            float* s0 = &scratch[SOa];
            float* s1 = &scratch[SOa + SRa];
            *(float4*)s0       = make_float4(acc0[0], acc0[1], acc0[2], acc0[3]);
            *(float4*)(s0 + 4) = make_float4(acc0[4], acc0[5], acc0[6], acc0[7]);
            *(float4*)s1       = make_float4(acc1[0], acc1[1], acc1[2], acc1[3]);
            *(float4*)(s1 + 4) = make_float4(acc1[4], acc1[5], acc1[6], acc1[7]);
        }
        // prefetch att1 weights (consumed 2 barriers later)
        if (tid < 256) {
#pragma unroll
            for (int k = 0; k < 8; ++k) pf1[k] = *(const float4*)(WB1 + (size_t)k * 256);
        }
        BAR();
        // ============ stage A reduce + gates -> c, h ============
        if (tid < 256) {
            const int r = gr_r, u = gr_u;
            float s[4];
#pragma unroll
            for (int q = 0; q < 4; ++q) {
                const int c4 = q * 128 + u;
                float v = g0p[q];
#pragma unroll
                for (int kc = 0; kc < 6; ++kc) v += scratch[kc * 1024 + r * 512 + c4];
                s[q] = v;
            }
            const float f  = sigf(s[0]);
            const float ig = sigf(s[1]);
            const float o  = sigf(s[2]);
            const float ch = tanhf(s[3]);
            const float c = f * cst[r][u] + ig * ch;
            cst[r][u] = c;
            hz[r][u] = tanhf(c) * o;
        } else if (tid < 384) {
            const int r = gr_r, cell = g12_cell, uu = g12_uu;
            float s[4];
#pragma unroll
            for (int q = 0; q < 4; ++q) {
                float v = __half2float(g12p[q]);
#pragma unroll
                for (int kc = 0; kc < 3; ++kc)
                    v += scratch[6144 + kc * 512 + r * 256 + cell * 128 + q * 32 + uu];
                s[q] = v;
            }
            const float f  = sigf(s[0]);
            const float ig = sigf(s[1]);
            const float o  = sigf(s[2]);
            const float ch = tanhf(s[3]);
            const int si = 128 + 32 * cell + uu;
            const float c = f * cst[r][si] + ig * ch;
            cst[r][si] = c;
            hz[r][si] = tanhf(c) * o;
        }
        BAR();
        // ============ att1 compute: 32 groups x 8 K-chunks of 24 ============
        if (tid < 256) {
            float acc0[8], acc1[8];
#pragma unroll
            for (int j = 0; j < 8; ++j) { acc0[j] = 0.f; acc1[j] = 0.f; }
#pragma unroll
            for (int k = 0; k < 8; ++k) {
                const __half* hw = (const __half*)&pf1[k];
                const float a0 = hz[0][HO1 + k];
                const float a1 = hz[1][HO1 + k];
#pragma unroll
                for (int j = 0; j < 8; ++j) {
                    const float w = __half2float(hw[j]);
                    acc0[j] += w * a0;
                    acc1[j] += w * a1;
                }
            }
#pragma unroll 8
            for (int k = 8; k < 24; ++k) {
                const float4 wv = *(const float4*)(WB1 + (size_t)k * 256);
                const __half* hw = (const __half*)&wv;
                const float a0 = hz[0][HO1 + k];
                const float a1 = hz[1][HO1 + k];
#pragma unroll
                for (int j = 0; j < 8; ++j) {
                    const float w = __half2float(hw[j]);
                    acc0[j] += w * a0;
                    acc1[j] += w * a1;
                }
            }
            float* s0 = &scratch[SO1];
            float* s1 = &scratch[SO1 + 256];
            *(float4*)s0       = make_float4(acc0[0], acc0[1], acc0[2], acc0[3]);
            *(float4*)(s0 + 4) = make_float4(acc0[4], acc0[5], acc0[6], acc0[7]);
            *(float4*)s1       = make_float4(acc1[0], acc1[1], acc1[2], acc1[3]);
            *(float4*)(s1 + 4) = make_float4(acc1[4], acc1[5], acc1[6], acc1[7]);
        }
        // prefetch att2 weights (consumed 2 barriers later)
        if (tid < 384) {
#pragma unroll
            for (int k = 0; k < 8; ++k) pf2[k] = *(const float4*)(WB2 + (size_t)k * 768);
        }
        BAR();
        // ============ att1 reduce + relu ============
        {
            const int r = tid >> 8, col = tid & 255;
            float s = ab1[col];
#pragma unroll
            for (int kc = 0; kc < 8; ++kc) s += scratch[kc * 512 + r * 256 + col];
            a1s[r][col] = fmaxf(s, 0.f);
        }
        BAR();
        // ============ att2 compute: 96 groups x 4 K-chunks of 64 ============
        if (tid < 384) {
            float acc0[8], acc1[8];
#pragma unroll
            for (int j = 0; j < 8; ++j) { acc0[j] = 0.f; acc1[j] = 0.f; }
#pragma unroll
            for (int k = 0; k < 8; ++k) {
                const __half* hw = (const __half*)&pf2[k];
                const float a0 = a1s[0][HO2 + k];
                const float a1 = a1s[1][HO2 + k];
#pragma unroll
                for (int j = 0; j < 8; ++j) {
                    const float w = __half2float(hw[j]);
                    acc0[j] += w * a0;
                    acc1[j] += w * a1;
                }
            }
#pragma unroll 8
            for (int k = 8; k < 64; ++k) {
                const float4 wv = *(const float4*)(WB2 + (size_t)k * 768);
                const __half* hw = (const __half*)&wv;
                const float a0 = a1s[0][HO2 + k];
                const float a1 = a1s[1][HO2 + k];
#pragma unroll
                for (int j = 0; j < 8; ++j) {
                    const float w = __half2float(hw[j]);
                    acc0[j] += w * a0;
                    acc1[j] += w * a1;
                }
            }
            float* s0 = &scratch[SO2];
            float* s1 = &scratch[SO2 + 768];
            *(float4*)s0       = make_float4(acc0[0], acc0[1], acc0[2], acc0[3]);
            *(float4*)(s0 + 4) = make_float4(acc0[4], acc0[5], acc0[6], acc0[7]);
            *(float4*)s1       = make_float4(acc1[0], acc1[1], acc1[2], acc1[3]);
            *(float4*)(s1 + 4) = make_float4(acc1[4], acc1[5], acc1[6], acc1[7]);
        }
        // prefetch comp1 weights (consumed 4 barriers later)
        if (tid < 320) {
#pragma unroll
            for (int k = 0; k < 8; ++k) pfc[k] = *(const float4*)(WBc + (size_t)k * KNc);
        }
        BAR();
        // ============ att2 reduce + sigmoid + exp ============
#pragma unroll
        for (int i = 0; i < 3; ++i) {
            const int idx = i * 512 + tid;
            const int r = idx >= 768;
            const int col = idx - r * 768;
            float s = ab2[col];
#pragma unroll
            for (int kc = 0; kc < 4; ++kc) s += scratch[kc * 1536 + r * 768 + col];
            attE[r][col] = expf(sigf(s));
        }
        BAR();
        // ============ softmax denominators ============
        {
            const int w = tid >> 6, lane = tid & 63;
            const int r = w >> 2, a = w & 3;
            float v = attE[r][a * 192 + lane] + attE[r][a * 192 + 64 + lane]
                    + attE[r][a * 192 + 128 + lane];
#pragma unroll
            for (int s = 32; s >= 1; s >>= 1) v += __shfl_xor(v, s);
            if (lane == 0) red[r][a] = v;
        }
        BAR();
        // ============ att_out = softmax * tiled(h) ============
#pragma unroll
        for (int i = 0; i < 3; ++i) {
            const int idx = i * 512 + tid;
            const int r = idx >= 768;
            const int col = idx - r * 768;
            const int a = col / 192;
            const float atv = attE[r][col] / red[r][a];
            const float ot = (col < 512) ? hz[r][col & 127]
                           : (col < 640) ? hz[r][128 + ((col - 512) & 31)]
                                         : hz[r][160 + ((col - 640) & 31)];
            aout[r][col] = atv * ot;
        }
        BAR();
        // ============ comp1 compute ============
        if (tid < 320) {
            float acc0[8], acc1[8];
#pragma unroll
            for (int j = 0; j < 8; ++j) { acc0[j] = 0.f; acc1[j] = 0.f; }
#pragma unroll
            for (int k = 0; k < 8; ++k) {
                const __half* hw = (const __half*)&pfc[k];
                const float a0 = aout[0][HOc + k];
                const float a1 = aout[1][HOc + k];
#pragma unroll
                for (int j = 0; j < 8; ++j) {
                    const float w = __half2float(hw[j]);
                    acc0[j] += w * a0;
                    acc1[j] += w * a1;
                }
            }
#pragma unroll
            for (int k = 8; k < 16; ++k) {
                const float4 wv = *(const float4*)(WBc + (size_t)k * KNc);
                const __half* hw = (const __half*)&wv;
                const float a0 = aout[0][HOc + k];
                const float a1 = aout[1][HOc + k];
#pragma unroll
                for (int j = 0; j < 8; ++j) {
                    const float w = __half2float(hw[j]);
                    acc0[j] += w * a0;
                    acc1[j] += w * a1;
                }
            }
            const int sr = (tid < 256) ? 64 : 32;
            float* s0 = &scratch[SOc];
            float* s1 = &scratch[SOc + sr];
            *(float4*)s0       = make_float4(acc0[0], acc0[1], acc0[2], acc0[3]);
            *(float4*)(s0 + 4) = make_float4(acc0[4], acc0[5], acc0[6], acc0[7]);
            *(float4*)s1       = make_float4(acc1[0], acc1[1], acc1[2], acc1[3]);
            *(float4*)(s1 + 4) = make_float4(acc1[4], acc1[5], acc1[6], acc1[7]);
        }
        BAR();
        // ============ comp1 reduce + relu ============
        if (tid < 256) {
            const int r = tid >> 7, col = tid & 127;
            float s;
            if (col < 64) {
                s = cb10[col];
#pragma unroll
                for (int kc = 0; kc < 32; ++kc) s += scratch[kc * 128 + r * 64 + col];
            } else {
                const int cc = col - 64;
                const int cell = cc >> 5, j = cc & 31;
                s = (cell ? cb12 : cb11)[j];
#pragma unroll
                for (int kc = 0; kc < 8; ++kc)
                    s += scratch[4096 + cell * 512 + kc * 64 + r * 32 + j];
            }
            hid[r][col] = fmaxf(s, 0.f);
        }
        BAR();
        // ============ comp2 + z softmax (LDS-resident weights) ============
        if (tid < 128) {
            const int r = tid >> 6, j = tid & 63;
            float acc;
            if (j < 32) {
                acc = cb20[j];
#pragma unroll
                for (int k = 0; k < 64; ++k) acc += hid[r][k] * c2w[k * 32 + j];
            } else if (j < 48) {
                const int o = j - 32; acc = cb21[o];
#pragma unroll
                for (int k = 0; k < 32; ++k) acc += hid[r][64 + k] * c2w[2048 + k * 16 + o];
            } else {
                const int o = j - 48; acc = cb22[o];
#pragma unroll
                for (int k = 0; k < 32; ++k) acc += hid[r][96 + k] * c2w[2560 + k * 16 + o];
            }
            const float e = expf(sigf(acc));
            float v = e;
#pragma unroll
            for (int s = 32; s >= 1; s >>= 1) v += __shfl_xor(v, s);
            hz[r][192 + j] = e / v;
        }
        // ============ prefetch next step: stage A weights + G values ======
        {
            const int tn = (t + 1 < TT) ? t + 1 : TT - 1;
            if (tid < 480) {
#pragma unroll
                for (int k = 0; k < 8; ++k) pfA[k] = *(const float4*)(WBa + (size_t)k * STRa);
            }
            if (tid < 256) {
                const float* gp = G0 + ((size_t)(row0 + gr_r) * TT + tn) * 512;
#pragma unroll
                for (int q = 0; q < 4; ++q) g0p[q] = gp[q * 128 + gr_u];
            } else if (tid < 384) {
                const __half* gp = (g12_cell ? G2h : G1h) + ((size_t)(row0 + gr_r) * TT + tn) * 128;
#pragma unroll
                for (int q = 0; q < 4; ++q) g12p[q] = gp[q * 32 + g12_uu];
            }
        }
        BAR();
    }

    __syncthreads();
    // ============ final MLP ============
    if (tid < 128) {
        const int r = tid >> 6, j = tid & 63;
        float acc = fb1[j];
#pragma unroll 8
        for (int k = 0; k < 64; ++k)  acc += hz[r][192 + k] * fw1[k * 64 + j];
#pragma unroll 8
        for (int k = 0; k < 192; ++k) acc += hz[r][k] * fw1[(64 + k) * 64 + j];
        hid[r][j] = fmaxf(acc, 0.f);
    }
    __syncthreads();
    if (tid < 128) {
        const int r = tid >> 6, j = tid & 63;
        float v = hid[r][j] * fw2[j];
#pragma unroll
        for (int s = 32; s >= 1; s >>= 1) v += __shfl_xor(v, s);
        if (j == 0) out[row0 + r] = v + fb2[0];
    }
}

// ---------------------------------------------------------------------------
extern "C" void kernel_launch(void* const* d_in, const int* in_sizes, int n_in,
                              void* d_out, int out_size, void* d_ws, size_t ws_size,
                              hipStream_t stream) {
    const float* x0   = (const float*)d_in[0];
    const float* x1   = (const float*)d_in[1];
    const float* x2   = (const float*)d_in[2];
    const float* W0   = (const float*)d_in[3];
    const float* U0   = (const float*)d_in[4];
    const float* V0   = (const float*)d_in[5];
    const float* b0   = (const float*)d_in[6];
    const float* W1   = (const float*)d_in[7];
    const float* U1   = (const float*)d_in[8];
    const float* V1   = (const float*)d_in[9];
    const float* b1   = (const float*)d_in[10];
    const float* W2   = (const float*)d_in[11];
    const float* U2   = (const float*)d_in[12];
    const float* V2   = (const float*)d_in[13];
    const float* b2   = (const float*)d_in[14];
    const float* aw1  = (const float*)d_in[15];
    const float* ab1  = (const float*)d_in[16];
    const float* aw2  = (const float*)d_in[17];
    const float* ab2  = (const float*)d_in[18];
    const float* cw10 = (const float*)d_in[19];
    const float* cb10 = (const float*)d_in[20];
    const float* cw20 = (const float*)d_in[21];
    const float* cb20 = (const float*)d_in[22];
    const float* cw11 = (const float*)d_in[23];
    const float* cb11 = (const float*)d_in[24];
    const float* cw21 = (const float*)d_in[25];
    const float* cb21 = (const float*)d_in[26];
    const float* cw12 = (const float*)d_in[27];
    const float* cb12 = (const float*)d_in[28];
    const float* cw22 = (const float*)d_in[29];
    const float* cb22 = (const float*)d_in[30];
    const float* fw1  = (const float*)d_in[31];
    const float* fb1  = (const float*)d_in[32];
    const float* fw2  = (const float*)d_in[33];
    const float* fb2  = (const float*)d_in[34];
    float* out = (float*)d_out;

    const size_t M = (size_t)BB * TT;   // 65536

    // workspace layout: G0 fp32, G1/G2 fp16, then fp16 weights
    float*  G0  = (float*)d_ws;                 // M*512 f32
    __half* G1h = (__half*)(G0 + M * 512);      // M*128 f16
    __half* G2h = G1h + M * 128;                // M*128 f16
    __half* hU0   = G2h + M * 128;   // 128*512 = 65536
    __half* hV0   = hU0 + 65536;     //  64*512 = 32768
    __half* hU1   = hV0 + 32768;     //  32*128 = 4096
    __half* hV1   = hU1 + 4096;      //  64*128 = 8192
    __half* hU2   = hV1 + 8192;      //  32*128 = 4096
    __half* hV2   = hU2 + 4096;      //  64*128 = 8192
    __half* haw1  = hV2 + 8192;      // 192*256 = 49152
    __half* haw2  = haw1 + 49152;    // 256*768 = 196608
    __half* hcw10 = haw2 + 196608;   // 512*64  = 32768
    __half* hcw11 = hcw10 + 32768;   // 128*32  = 4096
    __half* hcw12 = hcw11 + 4096;    // 128*32  = 4096

    // weight conversions
    f2h<<<(65536 + 255) / 256, 256, 0, stream>>>(U0, hU0, 65536);
    f2h<<<(32768 + 255) / 256, 256, 0, stream>>>(V0, hV0, 32768);
    f2h<<<(4096 + 255) / 256, 256, 0, stream>>>(U1, hU1, 4096);
    f2h<<<(8192 + 255) / 256, 256, 0, stream>>>(V1, hV1, 8192);
    f2h<<<(4096 + 255) / 256, 256, 0, stream>>>(U2, hU2, 4096);
    f2h<<<(8192 + 255) / 256, 256, 0, stream>>>(V2, hV2, 8192);
    f2h<<<(49152 + 255) / 256, 256, 0, stream>>>(aw1, haw1, 49152);
    f2h<<<(196608 + 255) / 256, 256, 0, stream>>>(aw2, haw2, 196608);
    f2h<<<(32768 + 255) / 256, 256, 0, stream>>>(cw10, hcw10, 32768);
    f2h<<<(4096 + 255) / 256, 256, 0, stream>>>(cw11, hcw11, 4096);
    f2h<<<(4096 + 255) / 256, 256, 0, stream>>>(cw12, hcw12, 4096);

    // G = x@W + b
    xw_gemm<float><<<dim3(512 / GT_N, M / GT_M), 256, 0, stream>>>(x0, W0, b0, G0, (int)M, 512, 300);
    xw_gemm<__half><<<dim3(128 / GT_N, M / GT_M), 256, 0, stream>>>(x1, W1, b1, G1h, (int)M, 128, 74);
    xw_gemm<__half><<<dim3(128 / GT_N, M / GT_M), 256, 0, stream>>>(x2, W2, b2, G2h, (int)M, 128, 35);

    // 128 blocks x 512 threads, 2 rows/block
    marn_rec<<<128, 512, 0, stream>>>(G0, G1h, G2h, hU0, hV0, hU1, hV1, hU2, hV2,
                                      haw1, ab1, haw2, ab2,
                                      hcw10, cb10, cw20, cb20,
                                      hcw11, cb11, cw21, cb21,
                                      hcw12, cb12, cw22, cb22,
                                      fw1, fb1, fw2, fb2, out);
}

// Round 5
// 7182.355 us; speedup vs baseline: 1.9111x; 1.9111x over previous
//
#include <hip/hip_runtime.h>
#include <hip/hip_bf16.h>
#include <hip/hip_fp16.h>
#include <math.h>

#define BB 256
#define TT 256
// H=[128,32,32], TH=192, ZDIM=64, ATT=4

__device__ __forceinline__ float sigf(float x) { return 1.f / (1.f + expf(-x)); }

// lgkm-only barrier: drains LDS ops; global loads may stay in flight.
#define BAR() do {                                   \
    __atomic_signal_fence(__ATOMIC_SEQ_CST);         \
    __builtin_amdgcn_s_waitcnt(0xC07F);              \
    __builtin_amdgcn_s_barrier();                    \
    __atomic_signal_fence(__ATOMIC_SEQ_CST);         \
} while (0)

__global__ void f2h(const float* __restrict__ s, __half* __restrict__ d, int n) {
    int i = blockIdx.x * 256 + threadIdx.x;
    if (i < n) d[i] = __float2half(s[i]);
}

// ---------------------------------------------------------------------------
// Kernel 1: G = X @ W + bias
// ---------------------------------------------------------------------------
#define GT_M 128
#define GT_N 64
#define GT_K 16

__device__ __forceinline__ void stvec4(float* p, float4 v) { *(float4*)p = v; }
__device__ __forceinline__ void stvec4(__half* p, float4 v) {
    *(__half2*)p = __floats2half2_rn(v.x, v.y);
    *(__half2*)(p + 2) = __floats2half2_rn(v.z, v.w);
}

template <typename OT>
__global__ __launch_bounds__(256)
void xw_gemm(const float* __restrict__ X, const float* __restrict__ W,
             const float* __restrict__ bias, OT* __restrict__ G,
             int M, int N, int K) {
    __shared__ float As[GT_K][GT_M + 4];
    __shared__ float Bs[GT_K][GT_N];
    const int tid = threadIdx.x;
    const int bm = blockIdx.y * GT_M;
    const int bn = blockIdx.x * GT_N;
    const int tx = tid & 15;
    const int ty = tid >> 4;

    float acc[8][4];
#pragma unroll
    for (int i = 0; i < 8; ++i)
#pragma unroll
        for (int j = 0; j < 4; ++j) acc[i][j] = 0.f;

    for (int kt = 0; kt < K; kt += GT_K) {
#pragma unroll
        for (int i = 0; i < 8; ++i) {
            int idx = i * 256 + tid;
            int m = idx >> 4, k = idx & 15;
            int gk = kt + k;
            As[k][m] = (gk < K) ? X[(size_t)(bm + m) * K + gk] : 0.f;
        }
#pragma unroll
        for (int i = 0; i < 4; ++i) {
            int idx = i * 256 + tid;
            int k = idx >> 6, n = idx & 63;
            int gk = kt + k;
            Bs[k][n] = (gk < K) ? W[(size_t)gk * N + bn + n] : 0.f;
        }
        __syncthreads();
#pragma unroll
        for (int k = 0; k < GT_K; ++k) {
            float a[8], b[4];
            const float4 a0 = *(const float4*)&As[k][ty * 8];
            const float4 a1 = *(const float4*)&As[k][ty * 8 + 4];
            const float4 bv = *(const float4*)&Bs[k][tx * 4];
            a[0]=a0.x; a[1]=a0.y; a[2]=a0.z; a[3]=a0.w;
            a[4]=a1.x; a[5]=a1.y; a[6]=a1.z; a[7]=a1.w;
            b[0]=bv.x; b[1]=bv.y; b[2]=bv.z; b[3]=bv.w;
#pragma unroll
            for (int i = 0; i < 8; ++i)
#pragma unroll
                for (int j = 0; j < 4; ++j) acc[i][j] += a[i] * b[j];
        }
        __syncthreads();
    }
    const int n0 = bn + tx * 4;
#pragma unroll
    for (int i = 0; i < 8; ++i) {
        int m = bm + ty * 8 + i;
        float4 v;
        v.x = acc[i][0] + bias[n0 + 0];
        v.y = acc[i][1] + bias[n0 + 1];
        v.z = acc[i][2] + bias[n0 + 2];
        v.w = acc[i][3] + bias[n0 + 3];
        stvec4(&G[(size_t)m * N + n0], v);
    }
}

// ---------------------------------------------------------------------------
// Kernel 2: persistent recurrence. 256 blocks x 512 threads, 1 row/block.
// fp16 weights, 8-col groups, lgkm-only barriers, unroll-16 k-loops,
// att_out fused into comp1, comp2 weights LDS-resident.
// ---------------------------------------------------------------------------
__global__ __launch_bounds__(512)
void marn_rec(const float* __restrict__ G0, const __half* __restrict__ G1h,
              const __half* __restrict__ G2h,
              const __half* __restrict__ hU0, const __half* __restrict__ hV0,
              const __half* __restrict__ hU1, const __half* __restrict__ hV1,
              const __half* __restrict__ hU2, const __half* __restrict__ hV2,
              const __half* __restrict__ haw1, const float* __restrict__ ab1,
              const __half* __restrict__ haw2, const float* __restrict__ ab2,
              const __half* __restrict__ hcw10, const float* __restrict__ cb10,
              const float* __restrict__ cw20, const float* __restrict__ cb20,
              const __half* __restrict__ hcw11, const float* __restrict__ cb11,
              const float* __restrict__ cw21, const float* __restrict__ cb21,
              const __half* __restrict__ hcw12, const float* __restrict__ cb12,
              const float* __restrict__ cw22, const float* __restrict__ cb22,
              const float* __restrict__ fw1, const float* __restrict__ fb1,
              const float* __restrict__ fw2, const float* __restrict__ fb2,
              float* __restrict__ out) {
    __shared__ float hz[256];     // [h0(128)|h1(32)|h2(32)|z(64)]
    __shared__ float cst[192];
    __shared__ float a1s[256];
    __shared__ float attE[768];
    __shared__ float hid[128];
    __shared__ float rinv[4];     // reciprocal softmax denominators
    __shared__ float scratch[3840];
    __shared__ float c2w[3072];   // cw20(2048)|cw21(512)|cw22(512)

    const int tid = threadIdx.x;
    const int row = blockIdx.x;

    for (int i = tid; i < 256; i += 512) hz[i] = 0.f;
    if (tid < 192) cst[tid] = 0.f;
    for (int i = tid; i < 2048; i += 512) c2w[i] = cw20[i];
    if (tid < 512) { c2w[2048 + tid] = cw21[tid]; c2w[2560 + tid] = cw22[tid]; }
    __syncthreads();

    // ---- stage A mapping (480 active) ----
    const __half* WBa = nullptr; int HOa = 0, STRa = 0, SOa = 0;
    if (tid < 384) {
        const int g = tid & 63, kc = tid >> 6;   // kc 0..5
        const int cb = g * 8;
        if (kc < 4) { WBa = hU0 + (size_t)(32 * kc) * 512 + cb; HOa = 32 * kc; }
        else        { WBa = hV0 + (size_t)(32 * (kc - 4)) * 512 + cb; HOa = 192 + 32 * (kc - 4); }
        STRa = 512;
        SOa = kc * 512 + cb;
    } else if (tid < 480) {
        const int u = tid - 384;                 // 0..95
        const int kc = u >> 5;                   // 0..2
        const int g2 = u & 31;
        const int cell = g2 >> 4;
        const int cb = (g2 & 15) * 8;
        const __half* Uc = cell ? hU2 : hU1;
        const __half* Vc = cell ? hV2 : hV1;
        if (kc == 0) { WBa = Uc + cb; HOa = 128 + 32 * cell; }
        else         { WBa = Vc + (size_t)(32 * (kc - 1)) * 128 + cb; HOa = 192 + 32 * (kc - 1); }
        STRa = 128;
        SOa = 3072 + kc * 256 + cell * 128 + cb;
    }
    // ---- att1 mapping (256 active) ----
    const __half* WB1 = nullptr; int HO1 = 0, SO1 = 0;
    if (tid < 256) {
        const int g = tid & 31, kc = tid >> 5;   // kc 0..7
        const int cb = g * 8;
        WB1 = haw1 + (size_t)(24 * kc) * 256 + cb;
        HO1 = 24 * kc;
        SO1 = kc * 256 + cb;
    }
    // ---- att2 mapping (384 active) ----
    const int kc2 = tid / 96;
    const int g2a = tid - kc2 * 96;
    const __half* WB2 = haw2 + (size_t)(64 * kc2) * 768 + g2a * 8;
    const int HO2 = 64 * kc2;
    const int SO2 = kc2 * 768 + g2a * 8;
    // ---- comp1 mapping (192 active), att_out fused ----
    const __half* WBc = nullptr; int HOc = 0, SOc = 0, KNc = 0, KLc = 0, HSELo = 0, HSELm = 0;
    if (tid < 128) {
        const int g = tid & 7, kc = tid >> 3;    // kc 0..15
        WBc = hcw10 + (size_t)(32 * kc) * 64 + g * 8;
        HOc = 32 * kc;
        SOc = kc * 64 + g * 8;
        KNc = 64; KLc = 32;
        HSELo = 0; HSELm = 127;
    } else if (tid < 192) {
        const int u = tid - 128;                 // 0..63
        const int cell = u >> 5;
        const int rem = u & 31;
        const int g = rem & 3, kc = rem >> 2;    // kc 0..7
        WBc = (cell ? hcw12 : hcw11) + (size_t)(16 * kc) * 32 + g * 8;
        HOc = 512 + 128 * cell + 16 * kc;
        SOc = 1024 + cell * 256 + kc * 32 + g * 8;
        KNc = 32; KLc = 16;
        HSELo = 128 + 32 * cell; HSELm = 31;
    }
    const int AHc = HOc / 192;                   // head idx (chunks never cross heads)
    const int HBc = (tid < 128) ? 0 : (512 + 128 * ((tid - 128) >> 5));
    // ---- gates / G-prefetch mapping (192 active) ----
    const int g12_cell = ((tid - 128) >> 5) & 1;
    const int g12_uu   = (tid - 128) & 31;

    float  g0p[4];
    __half g12p[4];
    if (tid < 128) {
        const float* gp = G0 + ((size_t)row * TT + 0) * 512;
#pragma unroll
        for (int q = 0; q < 4; ++q) g0p[q] = gp[q * 128 + tid];
    } else if (tid < 192) {
        const __half* gp = (g12_cell ? G2h : G1h) + ((size_t)row * TT + 0) * 128;
#pragma unroll
        for (int q = 0; q < 4; ++q) g12p[q] = gp[q * 32 + g12_uu];
    }

    for (int t = 0; t < TT; ++t) {
        // ======== stage A compute ========
        if (tid < 480) {
            float acc[8];
#pragma unroll
            for (int j = 0; j < 8; ++j) acc[j] = 0.f;
#pragma unroll 16
            for (int k = 0; k < 32; ++k) {
                const float4 wv = *(const float4*)(WBa + (size_t)k * STRa);
                const __half* hw = (const __half*)&wv;
                const float a0 = hz[HOa + k];
#pragma unroll
                for (int j = 0; j < 8; ++j) acc[j] += __half2float(hw[j]) * a0;
            }
            float* s0 = &scratch[SOa];
            *(float4*)s0       = make_float4(acc[0], acc[1], acc[2], acc[3]);
            *(float4*)(s0 + 4) = make_float4(acc[4], acc[5], acc[6], acc[7]);
        }
        BAR();
        // ======== gates ========
        if (tid < 128) {
            float s[4];
#pragma unroll
            for (int q = 0; q < 4; ++q) {
                const int c4 = q * 128 + tid;
                float v = g0p[q];
#pragma unroll
                for (int kc = 0; kc < 6; ++kc) v += scratch[kc * 512 + c4];
                s[q] = v;
            }
            const float f  = sigf(s[0]);
            const float ig = sigf(s[1]);
            const float o  = sigf(s[2]);
            const float ch = tanhf(s[3]);
            const float c = f * cst[tid] + ig * ch;
            cst[tid] = c;
            hz[tid] = tanhf(c) * o;
        } else if (tid < 192) {
            const int cell = g12_cell, uu = g12_uu;
            float s[4];
#pragma unroll
            for (int q = 0; q < 4; ++q) {
                float v = __half2float(g12p[q]);
#pragma unroll
                for (int kc = 0; kc < 3; ++kc)
                    v += scratch[3072 + kc * 256 + cell * 128 + q * 32 + uu];
                s[q] = v;
            }
            const float f  = sigf(s[0]);
            const float ig = sigf(s[1]);
            const float o  = sigf(s[2]);
            const float ch = tanhf(s[3]);
            const int si = 128 + 32 * cell + uu;
            const float c = f * cst[si] + ig * ch;
            cst[si] = c;
            hz[si] = tanhf(c) * o;
        }
        BAR();
        // ======== att1 compute ========
        if (tid < 256) {
            float acc[8];
#pragma unroll
            for (int j = 0; j < 8; ++j) acc[j] = 0.f;
#pragma unroll 8
            for (int k = 0; k < 24; ++k) {
                const float4 wv = *(const float4*)(WB1 + (size_t)k * 256);
                const __half* hw = (const __half*)&wv;
                const float a0 = hz[HO1 + k];
#pragma unroll
                for (int j = 0; j < 8; ++j) acc[j] += __half2float(hw[j]) * a0;
            }
            float* s0 = &scratch[SO1];
            *(float4*)s0       = make_float4(acc[0], acc[1], acc[2], acc[3]);
            *(float4*)(s0 + 4) = make_float4(acc[4], acc[5], acc[6], acc[7]);
        }
        BAR();
        // ======== att1 reduce + relu ========
        if (tid < 256) {
            float s = ab1[tid];
#pragma unroll
            for (int kc = 0; kc < 8; ++kc) s += scratch[kc * 256 + tid];
            a1s[tid] = fmaxf(s, 0.f);
        }
        BAR();
        // ======== att2 compute ========
        if (tid < 384) {
            float acc[8];
#pragma unroll
            for (int j = 0; j < 8; ++j) acc[j] = 0.f;
#pragma unroll 16
            for (int k = 0; k < 64; ++k) {
                const float4 wv = *(const float4*)(WB2 + (size_t)k * 768);
                const __half* hw = (const __half*)&wv;
                const float a0 = a1s[HO2 + k];
#pragma unroll
                for (int j = 0; j < 8; ++j) acc[j] += __half2float(hw[j]) * a0;
            }
            float* s0 = &scratch[SO2];
            *(float4*)s0       = make_float4(acc[0], acc[1], acc[2], acc[3]);
            *(float4*)(s0 + 4) = make_float4(acc[4], acc[5], acc[6], acc[7]);
        }
        BAR();
        // ======== att2 reduce + sigmoid + exp ========
#pragma unroll
        for (int i = 0; i < 2; ++i) {
            const int idx = i * 512 + tid;
            if (idx < 768) {
                float s = ab2[idx];
#pragma unroll
                for (int kc = 0; kc < 4; ++kc) s += scratch[kc * 768 + idx];
                attE[idx] = expf(sigf(s));
            }
        }
        BAR();
        // ======== softmax reciprocal denominators ========
        if (tid < 256) {
            const int a = tid >> 6, lane = tid & 63;
            float v = attE[a * 192 + lane] + attE[a * 192 + 64 + lane]
                    + attE[a * 192 + 128 + lane];
#pragma unroll
            for (int s = 32; s >= 1; s >>= 1) v += __shfl_xor(v, s);
            if (lane == 0) rinv[a] = 1.f / v;
        }
        BAR();
        // ======== comp1 compute (att_out fused) ========
        if (tid < 192) {
            const float ri = rinv[AHc];
            float acc[8];
#pragma unroll
            for (int j = 0; j < 8; ++j) acc[j] = 0.f;
#pragma unroll 8
            for (int k = 0; k < KLc; ++k) {
                const int idx = HOc + k;
                const float4 wv = *(const float4*)(WBc + (size_t)k * KNc);
                const __half* hw = (const __half*)&wv;
                const float ot = hz[HSELo + ((idx - HBc) & HSELm)];
                const float a0 = attE[idx] * ri * ot;
#pragma unroll
                for (int j = 0; j < 8; ++j) acc[j] += __half2float(hw[j]) * a0;
            }
            float* s0 = &scratch[SOc];
            *(float4*)s0       = make_float4(acc[0], acc[1], acc[2], acc[3]);
            *(float4*)(s0 + 4) = make_float4(acc[4], acc[5], acc[6], acc[7]);
        }
        BAR();
        // ======== comp1 reduce + relu ========
        if (tid < 128) {
            float s;
            if (tid < 64) {
                s = cb10[tid];
#pragma unroll
                for (int kc = 0; kc < 16; ++kc) s += scratch[kc * 64 + tid];
            } else {
                const int cc = tid - 64;
                const int cell = cc >> 5, j = cc & 31;
                s = (cell ? cb12 : cb11)[j];
#pragma unroll
                for (int kc = 0; kc < 8; ++kc)
                    s += scratch[1024 + cell * 256 + kc * 32 + j];
            }
            hid[tid] = fmaxf(s, 0.f);
        }
        BAR();
        // ======== comp2 + z softmax (one wave) ========
        if (tid < 64) {
            const int j = tid;
            float acc;
            if (j < 32) {
                acc = cb20[j];
#pragma unroll
                for (int k = 0; k < 64; ++k) acc += hid[k] * c2w[k * 32 + j];
            } else if (j < 48) {
                const int o = j - 32; acc = cb21[o];
#pragma unroll
                for (int k = 0; k < 32; ++k) acc += hid[64 + k] * c2w[2048 + k * 16 + o];
            } else {
                const int o = j - 48; acc = cb22[o];
#pragma unroll
                for (int k = 0; k < 32; ++k) acc += hid[96 + k] * c2w[2560 + k * 16 + o];
            }
            const float e = expf(sigf(acc));
            float v = e;
#pragma unroll
            for (int s = 32; s >= 1; s >>= 1) v += __shfl_xor(v, s);
            hz[192 + j] = e / v;
        }
        // ======== G prefetch for t+1 ========
        {
            const int tn = (t + 1 < TT) ? t + 1 : TT - 1;
            if (tid < 128) {
                const float* gp = G0 + ((size_t)row * TT + tn) * 512;
#pragma unroll
                for (int q = 0; q < 4; ++q) g0p[q] = gp[q * 128 + tid];
            } else if (tid < 192) {
                const __half* gp = (g12_cell ? G2h : G1h) + ((size_t)row * TT + tn) * 128;
#pragma unroll
                for (int q = 0; q < 4; ++q) g12p[q] = gp[q * 32 + g12_uu];
            }
        }
        BAR();
    }

    __syncthreads();
    // ======== final MLP ========
    if (tid < 64) {
        const int j = tid;
        float acc = fb1[j];
#pragma unroll 8
        for (int k = 0; k < 64; ++k)  acc += hz[192 + k] * fw1[k * 64 + j];
#pragma unroll 8
        for (int k = 0; k < 192; ++k) acc += hz[k] * fw1[(64 + k) * 64 + j];
        hid[j] = fmaxf(acc, 0.f);
    }
    __syncthreads();
    if (tid < 64) {
        float v = hid[tid] * fw2[tid];
#pragma unroll
        for (int s = 32; s >= 1; s >>= 1) v += __shfl_xor(v, s);
        if (tid == 0) out[row] = v + fb2[0];
    }
}

// ---------------------------------------------------------------------------
extern "C" void kernel_launch(void* const* d_in, const int* in_sizes, int n_in,
                              void* d_out, int out_size, void* d_ws, size_t ws_size,
                              hipStream_t stream) {
    const float* x0   = (const float*)d_in[0];
    const float* x1   = (const float*)d_in[1];
    const float* x2   = (const float*)d_in[2];
    const float* W0   = (const float*)d_in[3];
    const float* U0   = (const float*)d_in[4];
    const float* V0   = (const float*)d_in[5];
    const float* b0   = (const float*)d_in[6];
    const float* W1   = (const float*)d_in[7];
    const float* U1   = (const float*)d_in[8];
    const float* V1   = (const float*)d_in[9];
    const float* b1   = (const float*)d_in[10];
    const float* W2   = (const float*)d_in[11];
    const float* U2   = (const float*)d_in[12];
    const float* V2   = (const float*)d_in[13];
    const float* b2   = (const float*)d_in[14];
    const float* aw1  = (const float*)d_in[15];
    const float* ab1  = (const float*)d_in[16];
    const float* aw2  = (const float*)d_in[17];
    const float* ab2  = (const float*)d_in[18];
    const float* cw10 = (const float*)d_in[19];
    const float* cb10 = (const float*)d_in[20];
    const float* cw20 = (const float*)d_in[21];
    const float* cb20 = (const float*)d_in[22];
    const float* cw11 = (const float*)d_in[23];
    const float* cb11 = (const float*)d_in[24];
    const float* cw21 = (const float*)d_in[25];
    const float* cb21 = (const float*)d_in[26];
    const float* cw12 = (const float*)d_in[27];
    const float* cb12 = (const float*)d_in[28];
    const float* cw22 = (const float*)d_in[29];
    const float* cb22 = (const float*)d_in[30];
    const float* fw1  = (const float*)d_in[31];
    const float* fb1  = (const float*)d_in[32];
    const float* fw2  = (const float*)d_in[33];
    const float* fb2  = (const float*)d_in[34];
    float* out = (float*)d_out;

    const size_t M = (size_t)BB * TT;   // 65536

    float*  G0  = (float*)d_ws;                 // M*512 f32
    __half* G1h = (__half*)(G0 + M * 512);      // M*128 f16
    __half* G2h = G1h + M * 128;                // M*128 f16
    __half* hU0   = G2h + M * 128;
    __half* hV0   = hU0 + 65536;
    __half* hU1   = hV0 + 32768;
    __half* hV1   = hU1 + 4096;
    __half* hU2   = hV1 + 8192;
    __half* hV2   = hU2 + 4096;
    __half* haw1  = hV2 + 8192;
    __half* haw2  = haw1 + 49152;
    __half* hcw10 = haw2 + 196608;
    __half* hcw11 = hcw10 + 32768;
    __half* hcw12 = hcw11 + 4096;

    f2h<<<(65536 + 255) / 256, 256, 0, stream>>>(U0, hU0, 65536);
    f2h<<<(32768 + 255) / 256, 256, 0, stream>>>(V0, hV0, 32768);
    f2h<<<(4096 + 255) / 256, 256, 0, stream>>>(U1, hU1, 4096);
    f2h<<<(8192 + 255) / 256, 256, 0, stream>>>(V1, hV1, 8192);
    f2h<<<(4096 + 255) / 256, 256, 0, stream>>>(U2, hU2, 4096);
    f2h<<<(8192 + 255) / 256, 256, 0, stream>>>(V2, hV2, 8192);
    f2h<<<(49152 + 255) / 256, 256, 0, stream>>>(aw1, haw1, 49152);
    f2h<<<(196608 + 255) / 256, 256, 0, stream>>>(aw2, haw2, 196608);
    f2h<<<(32768 + 255) / 256, 256, 0, stream>>>(cw10, hcw10, 32768);
    f2h<<<(4096 + 255) / 256, 256, 0, stream>>>(cw11, hcw11, 4096);
    f2h<<<(4096 + 255) / 256, 256, 0, stream>>>(cw12, hcw12, 4096);

    xw_gemm<float><<<dim3(512 / GT_N, M / GT_M), 256, 0, stream>>>(x0, W0, b0, G0, (int)M, 512, 300);
    xw_gemm<__half><<<dim3(128 / GT_N, M / GT_M), 256, 0, stream>>>(x1, W1, b1, G1h, (int)M, 128, 74);
    xw_gemm<__half><<<dim3(128 / GT_N, M / GT_M), 256, 0, stream>>>(x2, W2, b2, G2h, (int)M, 128, 35);

    // 256 blocks x 512 threads, 1 row/block
    marn_rec<<<256, 512, 0, stream>>>(G0, G1h, G2h, hU0, hV0, hU1, hV1, hU2, hV2,
                                      haw1, ab1, haw2, ab2,
                                      hcw10, cb10, cw20, cb20,
                                      hcw11, cb11, cw21, cb21,
                                      hcw12, cb12, cw22, cb22,
                                      fw1, fb1, fw2, fb2, out);
}